// Round 15
// baseline (818.269 us; speedup 1.0000x reference)
//
#include <hip/hip_runtime.h>
#include <hip/hip_bf16.h>

// Problem constants (DecoderRNN): B=64, S=64, IMG_F=2048, EMB=HID=512, VOCAB=32000
#define B_    64
#define S_    64
#define T_    63      // S-1
#define IMGF  2048
#define EMB   512
#define HID   512
#define VOCAB 32000
#define MROWS 4032    // B_*T_
#define MPAD  4096

typedef __bf16 bf16;
typedef __bf16 bf16x8 __attribute__((ext_vector_type(8)));
typedef float  f32x4  __attribute__((ext_vector_type(4)));

__device__ __forceinline__ void gload_lds16(const void* g, void* l) {
  __builtin_amdgcn_global_load_lds(
      (const __attribute__((address_space(1))) unsigned int*)g,
      (__attribute__((address_space(3))) unsigned int*)l, 16, 0, 0);
}

#define LGKM_BARRIER() asm volatile("s_waitcnt lgkmcnt(0)\n\ts_barrier" ::: "memory")

// ---------------------------------------------------------------------------
// Tiled transpose f32[K][N] -> bf16[N][K]  (64x64 tiles via LDS)
// ---------------------------------------------------------------------------
__global__ __launch_bounds__(256) void transpose_w(
    const float* __restrict__ W, bf16* __restrict__ WT, int K, int N)
{
  __shared__ float tile[64][65];
  const int tx = threadIdx.x & 63, ty = threadIdx.x >> 6;
  const int n0 = blockIdx.x * 64, k0 = blockIdx.y * 64;
  #pragma unroll
  for (int r = ty; r < 64; r += 4)
    tile[r][tx] = W[(size_t)(k0 + r) * N + n0 + tx];
  __syncthreads();
  #pragma unroll
  for (int r = ty; r < 64; r += 4)
    WT[(size_t)(n0 + r) * K + k0 + tx] = (bf16)tile[tx][r];
}

// ---------------------------------------------------------------------------
// Wy transpose into TILED + PRE-SWIZZLED blob (BK=64 layout, validated R14).
// Blob tile (bn, kt64): 2048 16B-chunks (256 rows x 8 slots); physical chunk
// rr*8+sl holds logical k-slot (sl ^ (rr&7)) of local row rr.
// ---------------------------------------------------------------------------
__global__ __launch_bounds__(256) void transpose_wy_tiled(
    const float* __restrict__ W, bf16* __restrict__ T)   // W: [HID][VOCAB]
{
  __shared__ float tile[64][65];
  const int tx = threadIdx.x & 63, ty = threadIdx.x >> 6;
  const int n0 = blockIdx.x * 64, k0 = blockIdx.y * 64;
  #pragma unroll
  for (int r = ty; r < 64; r += 4)
    tile[r][tx] = W[(size_t)(k0 + r) * VOCAB + n0 + tx];
  __syncthreads();
  #pragma unroll
  for (int r = ty; r < 64; r += 4) {
    const int n = n0 + r, k = k0 + tx;
    const int bn = n >> 8, rr = n & 255;
    const int kt = k >> 6;                       // 0..7
    const int sl = ((k & 63) >> 3) ^ (rr & 7);
    const size_t dst = (((size_t)(bn * 8 + kt) * 2048 + rr * 8 + sl) << 3)
                     + (k & 7);
    T[dst] = (bf16)tile[tx][r];
  }
}

// ---------------------------------------------------------------------------
// Embedding gather (bf16 out, rows >= MROWS zeroed)
// ---------------------------------------------------------------------------
__global__ __launch_bounds__(256) void embed_gather(
    const float* __restrict__ embW, const int* __restrict__ captions,
    bf16* __restrict__ X)
{
  const int r = blockIdx.x;
  const int tid = threadIdx.x;
  if (r < MROWS) {
    const int b = r / T_, t = r % T_;
    const int idx = captions[b * S_ + t];
    float2 v = ((const float2*)(embW + (size_t)idx * EMB))[tid];
    X[(size_t)r * EMB + 2 * tid]     = (bf16)v.x;
    X[(size_t)r * EMB + 2 * tid + 1] = (bf16)v.y;
  } else {
    X[(size_t)r * EMB + 2 * tid]     = (bf16)0.f;
    X[(size_t)r * EMB + 2 * tid + 1] = (bf16)0.f;
  }
}

// ---------------------------------------------------------------------------
// img -> bf16, padded to 128 rows
// ---------------------------------------------------------------------------
__global__ __launch_bounds__(256) void img_to_bf16(
    const float* __restrict__ img, bf16* __restrict__ imgB)
{
  const int r = blockIdx.x;
  const int tid = threadIdx.x;
  #pragma unroll
  for (int j = 0; j < 8; j++) {
    const int c = tid + j * 256;
    const float v = (r < B_) ? img[(size_t)r * IMGF + c] : 0.f;
    imgB[(size_t)r * IMGF + c] = (bf16)v;
  }
}

// ---------------------------------------------------------------------------
// bf16 MFMA GEMM, 128x128 tile, 2-phase (small pre/pimg GEMMs)
// ---------------------------------------------------------------------------
__global__ __launch_bounds__(256) void gemm_bt(
    const bf16* __restrict__ A, const bf16* __restrict__ BT,
    const float* __restrict__ bias, float* __restrict__ C,
    int Mvalid, int N, int K)
{
  __shared__ __align__(16) bf16 As[2][128 * 32];
  __shared__ __align__(16) bf16 Bs[2][128 * 32];
  const int tid  = threadIdx.x;
  const int wave = tid >> 6, lane = tid & 63;
  const int wm = wave >> 1, wn = wave & 1;
  const int bm = blockIdx.x, bn = blockIdx.y;
  const int lg = lane >> 4, lr = lane & 15;

  f32x4 acc[4][4];
  #pragma unroll
  for (int m = 0; m < 4; m++)
    #pragma unroll
    for (int n = 0; n < 4; n++) acc[m][n] = (f32x4){0.f, 0.f, 0.f, 0.f};

  const bf16* Abase = A  + (size_t)bm * 128 * K;
  const bf16* Bbase = BT + (size_t)bn * 128 * K;

  const int c0 = wave * 64 + lane;
  const int r0 = c0 >> 2,  sl0 = (c0 & 3) ^ ((r0 >> 1) & 3);
  const int c1 = 256 + c0;
  const int r1 = c1 >> 2,  sl1 = (c1 & 3) ^ ((r1 >> 1) & 3);

  const int NT = K >> 5;

#define STAGE_TILE(buf, kt)                                                   \
  do {                                                                        \
    gload_lds16(Abase + (size_t)r0 * K + (kt) + sl0 * 8,                      \
                &As[buf][(wave * 64) * 8]);                                   \
    gload_lds16(Abase + (size_t)r1 * K + (kt) + sl1 * 8,                      \
                &As[buf][(256 + wave * 64) * 8]);                             \
    gload_lds16(Bbase + (size_t)r0 * K + (kt) + sl0 * 8,                      \
                &Bs[buf][(wave * 64) * 8]);                                   \
    gload_lds16(Bbase + (size_t)r1 * K + (kt) + sl1 * 8,                      \
                &Bs[buf][(256 + wave * 64) * 8]);                             \
  } while (0)

  STAGE_TILE(0, 0);
  int cur = 0;
  for (int it = 0; it < NT; ++it) {
    __syncthreads();
    if (it + 1 < NT) STAGE_TILE(cur ^ 1, (it + 1) * 32);

    bf16x8 af[4], bfr[4];
    #pragma unroll
    for (int m = 0; m < 4; m++) {
      const int r = wm * 64 + m * 16 + lr;
      const int sp = lg ^ ((r >> 1) & 3);
      af[m] = *(const bf16x8*)&As[cur][r * 32 + sp * 8];
    }
    #pragma unroll
    for (int n = 0; n < 4; n++) {
      const int r = wn * 64 + n * 16 + lr;
      const int sp = lg ^ ((r >> 1) & 3);
      bfr[n] = *(const bf16x8*)&Bs[cur][r * 32 + sp * 8];
    }
    #pragma unroll
    for (int m = 0; m < 4; m++)
      #pragma unroll
      for (int n = 0; n < 4; n++)
        acc[m][n] = __builtin_amdgcn_mfma_f32_16x16x32_bf16(af[m], bfr[n], acc[m][n], 0, 0, 0);
    cur ^= 1;
  }
#undef STAGE_TILE

  const int row0 = bm * 128 + wm * 64 + (lane >> 4) * 4;
  const int col0 = bn * 128 + wn * 64 + lr;
  #pragma unroll
  for (int m = 0; m < 4; m++) {
    #pragma unroll
    for (int n = 0; n < 4; n++) {
      const int col = col0 + n * 16;
      const float bv = bias[col];
      #pragma unroll
      for (int q = 0; q < 4; q++) {
        const int row = row0 + m * 16 + q;
        if (row < Mvalid) C[(size_t)row * N + col] = acc[m][n][q] + bv;
      }
    }
  }
}

// ---------------------------------------------------------------------------
// FUSED producer-consumer, STATIC work assignment.
// Blocks 0-3: RNN producers (R14 body; hs T-MAJOR row = t*64+b; progress
//   published every 4th step via vmcnt-draining __syncthreads + release store
//   — sync mechanism validated in R13).
// Blocks 4..253: worker u=w-4 owns B panel bn=u>>1 and M-half half=u&1
//   (M=128). Walks bm=0..15 in readiness order: spins until ctrl[0..3] >=
//   min(4bm+4,63), acquire-fence, then K-loop = R14-validated 2-buf
//   counted-vmcnt(6), epilogue = R12-validated LDS-staged stores.
// Locality: each worker re-reads only its own 256KB B panel (L2-resident);
//   A (4MB) from L3. Fixes R13's 278MB FETCH (queue destroyed locality).
// Deadlock safety: 256 blocks x 144KB LDS -> 1 block/CU -> all co-resident.
// ---------------------------------------------------------------------------
#define FREG 48
#define FLDS 16   // 64 - FREG
__global__ __launch_bounds__(512, 1) void rnn_gemm(
    const float* __restrict__ pre, const bf16* __restrict__ WhT,
    const float* __restrict__ bh, const float* __restrict__ pimg,
    bf16* __restrict__ hs, const bf16* __restrict__ Btile,
    const float* __restrict__ by, float* __restrict__ C,
    unsigned* ctrl)   // ctrl[0..3] = progress
{
  __shared__ __align__(16) char smem[147456];   // 144 KB union
  const int tid  = threadIdx.x;
  const int wave = tid >> 6, lane = tid & 63;
  const int lg = lane >> 4, lr = lane & 15;

  // ===================== RNN producers (blocks 0-3) ========================
  if (blockIdx.x < 4) {
    const int bg  = blockIdx.x;
    const int gb0 = bg * 16;
    const int wc0 = wave * 64;
    bf16* hsh = (bf16*)smem;                  // 16 KB
    bf16* bls = (bf16*)(smem + 16384);        // 128 KB

    bf16x8 bw[FREG];
    #pragma unroll
    for (int f = 0; f < 64; f++) {
      const int n = f >> 4, kf = f & 15;
      const bf16x8 v = *(const bf16x8*)(WhT + (size_t)(wc0 + n * 16 + lr) * 512
                                            + kf * 32 + lg * 8);
      if (f < FREG) bw[f] = v;
      else *(bf16x8*)&bls[((wave * FLDS + (f - FREG)) * 64 + lane) * 8] = v;
    }

    *(f32x4*)&hsh[tid * 16]     = (f32x4){0.f, 0.f, 0.f, 0.f};
    *(f32x4*)&hsh[tid * 16 + 8] = (f32x4){0.f, 0.f, 0.f, 0.f};

    float bhv[4];
    #pragma unroll
    for (int n = 0; n < 4; n++) bhv[n] = bh[wc0 + n * 16 + lr];
    const float* preb = pre + ((size_t)(gb0 + lg * 4) * T_) * 512 + wc0 + lr;

    __syncthreads();

    #pragma unroll 1
    for (int t = 0; t < T_; t++) {
      float prq[4][4];
      #pragma unroll
      for (int n = 0; n < 4; n++)
        #pragma unroll
        for (int q = 0; q < 4; q++)
          prq[n][q] = preb[(size_t)q * (T_ * 512) + (size_t)t * 512 + n * 16];

      f32x4 acc[4];
      #pragma unroll
      for (int n = 0; n < 4; n++) acc[n] = (f32x4){0.f, 0.f, 0.f, 0.f};

      #pragma unroll
      for (int kf = 0; kf < 16; kf++) {
        const int c = (kf * 4 + lg) ^ (lr & 7);
        const bf16x8 a = *(const bf16x8*)&hsh[(lr * 64 + c) * 8];
        #pragma unroll
        for (int n = 0; n < 4; n++) {
          const int f = n * 16 + kf;
          bf16x8 bfrag;
          if (f < FREG) bfrag = bw[f];
          else bfrag = *(const bf16x8*)&bls[((wave * FLDS + (f - FREG)) * 64 + lane) * 8];
          acc[n] = __builtin_amdgcn_mfma_f32_16x16x32_bf16(a, bfrag, acc[n], 0, 0, 0);
        }
      }
      LGKM_BARRIER();

      #pragma unroll
      for (int n = 0; n < 4; n++) {
        #pragma unroll
        for (int q = 0; q < 4; q++) {
          const int bl = lg * 4 + q;
          const int b  = gb0 + bl;
          const int k  = wc0 + n * 16 + lr;
          float s = acc[n][q] + prq[n][q] + bhv[n];
          if (t == 0) s += pimg[(size_t)b * HID + k];
          const float e = __builtin_exp2f(s * 2.885390081777927f);
          const float hv = 1.f - 2.f * __builtin_amdgcn_rcpf(e + 1.f);
          hs[((size_t)t * 64 + b) * HID + k] = (bf16)hv;      // T-MAJOR
          const int c = (k >> 3) ^ (bl & 7);
          hsh[bl * 512 + c * 8 + (k & 7)] = (bf16)hv;
        }
      }
      if (((t + 1) & 3) == 0 || (t + 1) == T_) {
        __syncthreads();   // drains vmcnt(0): ALL waves' hs stores complete
        if (tid == 0)
          __hip_atomic_store(&ctrl[bg], (unsigned)(t + 1),
                             __ATOMIC_RELEASE, __HIP_MEMORY_SCOPE_AGENT);
      } else {
        LGKM_BARRIER();
      }
    }
    return;
  }

  // ===================== GEMM workers (blocks 4..253) ======================
  const int u = (int)blockIdx.x - 4;
  if (u >= 250) return;
  const int bn = u >> 1, half = u & 1;

  bf16* smA = (bf16*)smem;                 // [2][128*64] = 2 x 16 KB
  bf16* smB = (bf16*)(smem + 32768);       // [2][256*64] = 2 x 32 KB (96 KB tot)
  const int wm = wave >> 2, wn = wave & 3;

  // A staging map: 1024 chunks (128 rows x 8 slots), 2 per thread
  int raA[2], saA[2];
  #pragma unroll
  for (int i = 0; i < 2; i++) {
    const int c = tid + i * 512;
    raA[i] = c >> 3;
    saA[i] = (c & 7) ^ (raA[i] & 7);
  }

  #pragma unroll 1
  for (int bm = 0; bm < 16; ++bm) {
    // ---- wait until this M-tile's t-rows are produced ----
    if (tid == 0) {
      unsigned tneed = (unsigned)(4 * bm + 4);
      if (tneed > 63u) tneed = 63u;
      #pragma unroll
      for (int g = 0; g < 4; ++g) {
        int poll = 0;
        while (__hip_atomic_load(&ctrl[g], __ATOMIC_RELAXED,
                                 __HIP_MEMORY_SCOPE_AGENT) < tneed) {
          __builtin_amdgcn_s_sleep(8);
          if ((++poll & 63) == 0)
            (void)__hip_atomic_load(&ctrl[g], __ATOMIC_ACQUIRE,
                                    __HIP_MEMORY_SCOPE_AGENT);
        }
      }
    }
    __syncthreads();
    __builtin_amdgcn_fence(__ATOMIC_ACQUIRE, "agent");

    const bf16* Ab = hs + ((size_t)bm * 256 + half * 128) * 512;

    f32x4 acc[4][4];
    #pragma unroll
    for (int m = 0; m < 4; m++)
      #pragma unroll
      for (int n = 0; n < 4; n++) acc[m][n] = (f32x4){0.f, 0.f, 0.f, 0.f};

#define STAGEF(buf, kti)                                                      \
  do {                                                                        \
    const bf16* Bt_ = Btile + (((size_t)(bn * 8 + (kti))) << 14);             \
    _Pragma("unroll")                                                         \
    for (int i = 0; i < 2; i++)                                               \
      gload_lds16(Ab + (size_t)raA[i] * 512 + (kti) * 64 + saA[i] * 8,        \
                  &smA[((buf) * 1024 + i * 512 + wave * 64) * 8]);            \
    _Pragma("unroll")                                                         \
    for (int i = 0; i < 4; i++)                                               \
      gload_lds16(Bt_ + (size_t)(tid + i * 512) * 8,                          \
                  &smB[((buf) * 2048 + i * 512 + wave * 64) * 8]);            \
  } while (0)

    STAGEF(0, 0);
    STAGEF(1, 1);

    #pragma unroll 1
    for (int it = 0; it < 8; ++it) {
      if (it < 7) asm volatile("s_waitcnt vmcnt(6)\n\ts_barrier" ::: "memory");
      else        asm volatile("s_waitcnt vmcnt(0)\n\ts_barrier" ::: "memory");

      const bf16* As_ = smA + (it & 1) * 1024 * 8;
      const bf16* Bs_ = smB + (it & 1) * 2048 * 8;
      #pragma unroll
      for (int kk = 0; kk < 2; kk++) {
        bf16x8 af[4], bfr[4];
        #pragma unroll
        for (int m = 0; m < 4; m++) {
          const int r = wm * 64 + m * 16 + lr;          // 0..127 (A half)
          const int sp = (kk * 4 + lg) ^ (r & 7);
          af[m] = *(const bf16x8*)&As_[(r * 8 + sp) * 8];
        }
        #pragma unroll
        for (int n = 0; n < 4; n++) {
          const int r = wn * 64 + n * 16 + lr;          // 0..255 (B)
          const int sp = (kk * 4 + lg) ^ (r & 7);
          bfr[n] = *(const bf16x8*)&Bs_[(r * 8 + sp) * 8];
        }
        #pragma unroll
        for (int m = 0; m < 4; m++)
          #pragma unroll
          for (int n = 0; n < 4; n++)
            acc[m][n] = __builtin_amdgcn_mfma_f32_16x16x32_bf16(af[m], bfr[n], acc[m][n], 0, 0, 0);
      }

      LGKM_BARRIER();                  // all waves done READING buf[it]
      if (it + 2 < 8) STAGEF(it & 1, it + 2);
    }
#undef STAGEF

    // ---- LDS-staged epilogue (R12-validated), 2 passes of 64 rows ----
    float* cst = (float*)smem;                  // 64 rows x 256 f32 = 64 KB
    float bvv[4];
    #pragma unroll
    for (int n = 0; n < 4; n++)
      bvv[n] = by[bn * 256 + wn * 64 + n * 16 + lr];

    #pragma unroll
    for (int pass = 0; pass < 2; ++pass) {
      if (wm == pass) {
        #pragma unroll
        for (int m = 0; m < 4; m++)
          #pragma unroll
          for (int n = 0; n < 4; n++) {
            const int cc = wn * 64 + n * 16 + lr;
            #pragma unroll
            for (int q = 0; q < 4; q++)
              cst[(m * 16 + lg * 4 + q) * 256 + cc] = acc[m][n][q] + bvv[n];
          }
      }
      __syncthreads();
      const int rbase = bm * 256 + half * 128 + pass * 64;
      #pragma unroll
      for (int i = 0; i < 8; i++) {
        const int r = i * 8 + wave;               // 0..63
        const int grow = rbase + r;               // t-major global row
        const int tt = grow >> 6, bb = grow & 63;
        if (tt < T_) {
          const f32x4 v = *(const f32x4*)&cst[r * 256 + lane * 4];
          *(f32x4*)&C[(size_t)(bb * T_ + tt) * VOCAB + bn * 256 + lane * 4] = v;
        }
      }
      __syncthreads();
    }
  }
}

// ---------------------------------------------------------------------------
extern "C" void kernel_launch(void* const* d_in, const int* in_sizes, int n_in,
                              void* d_out, int out_size, void* d_ws, size_t ws_size,
                              hipStream_t stream) {
  const float* img      = (const float*)d_in[0];
  const int*   captions = (const int*)d_in[1];
  const float* embW     = (const float*)d_in[2];
  const float* Wi       = (const float*)d_in[3];
  const float* bi       = (const float*)d_in[4];
  const float* Wx       = (const float*)d_in[5];
  const float* bx       = (const float*)d_in[6];
  const float* Wh       = (const float*)d_in[7];
  const float* bh       = (const float*)d_in[8];
  const float* Wy       = (const float*)d_in[9];
  const float* by       = (const float*)d_in[10];
  float* logits = (float*)d_out;

  // workspace layout (52.8 MB)
  char* ws = (char*)d_ws;
  bf16*  WyT  = (bf16*)(ws);                   // tiled blob, 32,768,000 B
  bf16*  WxT  = (bf16*)(ws + 32768000);        //   512*512*2 =    524,288
  bf16*  X    = (bf16*)(ws + 33292288);        //  4096*512*2 =  4,194,304
  bf16*  hs   = (bf16*)(ws + 37486592);        //  4096*512*2 (T-MAJOR)
  float* pre  = (float*)(ws + 41680896);       //  4032*512*4 =  8,257,536
  float* pimg = (float*)(ws + 49938432);       //  rows 0-63 used
  unsigned* ctrl = (unsigned*)(ws + 50069504); //  256 B (dead half of pimg slot)
  bf16*  imgB = (bf16*)(ws + 50200576);        //  128*2048*2 =    524,288
  bf16*  WiT  = (bf16*)(ws + 50724864);        //  512*2048*2 =  2,097,152
  bf16*  WhT  = WxT;                           // alias: used only after pre-GEMM

  // 1) weight transposes / converts to bf16
  transpose_wy_tiled<<<dim3(VOCAB / 64, HID / 64), 256, 0, stream>>>(Wy, WyT);
  transpose_w<<<dim3(HID / 64, EMB / 64), 256, 0, stream>>>(Wx, WxT, EMB, HID);
  transpose_w<<<dim3(HID / 64, IMGF / 64), 256, 0, stream>>>(Wi, WiT, IMGF, HID);
  img_to_bf16<<<128, 256, 0, stream>>>(img, imgB);

  // 2) embedding gather
  embed_gather<<<MPAD, 256, 0, stream>>>(embW, captions, X);

  // 3) pre = X @ Wx + bx
  gemm_bt<<<dim3(MPAD / 128, HID / 128), 256, 0, stream>>>(X, WxT, bx, pre, MROWS, HID, HID);

  // 4) pimg = img @ Wi + bi
  gemm_bt<<<dim3(1, HID / 128), 256, 0, stream>>>(imgB, WiT, bi, pimg, B_, HID, IMGF);

  // 5) Wh -> bf16 [col][k]
  transpose_w<<<dim3(HID / 64, HID / 64), 256, 0, stream>>>(Wh, WhT, HID, HID);

  // 6) zero hs pad rows (t=63, same flat range as before) + control block
  hipMemsetAsync(hs + (size_t)MROWS * HID, 0,
                 (size_t)(MPAD - MROWS) * HID * sizeof(bf16), stream);
  hipMemsetAsync(ctrl, 0, 256, stream);

  // 7) FUSED RNN + logits GEMM (256 blocks, 1/CU co-resident; static work map)
  rnn_gemm<<<256, 512, 0, stream>>>(pre, WhT, bh, pimg, hs, WyT, by, logits, ctrl);
}

// Round 16
// 583.256 us; speedup vs baseline: 1.4029x; 1.4029x over previous
//
#include <hip/hip_runtime.h>
#include <hip/hip_bf16.h>

// Problem constants (DecoderRNN): B=64, S=64, IMG_F=2048, EMB=HID=512, VOCAB=32000
#define B_    64
#define S_    64
#define T_    63      // S-1
#define IMGF  2048
#define EMB   512
#define HID   512
#define VOCAB 32000
#define MROWS 4032    // B_*T_
#define MPAD  4096

typedef __bf16 bf16;
typedef __bf16 bf16x8 __attribute__((ext_vector_type(8)));
typedef float  f32x4  __attribute__((ext_vector_type(4)));

__device__ __forceinline__ void gload_lds16(const void* g, void* l) {
  __builtin_amdgcn_global_load_lds(
      (const __attribute__((address_space(1))) unsigned int*)g,
      (__attribute__((address_space(3))) unsigned int*)l, 16, 0, 0);
}

#define LGKM_BARRIER() asm volatile("s_waitcnt lgkmcnt(0)\n\ts_barrier" ::: "memory")

// ---------------------------------------------------------------------------
// Tiled transpose f32[K][N] -> bf16[N][K]  (64x64 tiles via LDS)
// ---------------------------------------------------------------------------
__global__ __launch_bounds__(256) void transpose_w(
    const float* __restrict__ W, bf16* __restrict__ WT, int K, int N)
{
  __shared__ float tile[64][65];
  const int tx = threadIdx.x & 63, ty = threadIdx.x >> 6;
  const int n0 = blockIdx.x * 64, k0 = blockIdx.y * 64;
  #pragma unroll
  for (int r = ty; r < 64; r += 4)
    tile[r][tx] = W[(size_t)(k0 + r) * N + n0 + tx];
  __syncthreads();
  #pragma unroll
  for (int r = ty; r < 64; r += 4)
    WT[(size_t)(n0 + r) * K + k0 + tx] = (bf16)tile[tx][r];
}

// ---------------------------------------------------------------------------
// Wy transpose into TILED + PRE-SWIZZLED blob (BK=64 layout, validated R14).
// Blob tile (bn, kt64): 2048 16B-chunks (256 rows x 8 slots); physical chunk
// rr*8+sl holds logical k-slot (sl ^ (rr&7)) of local row rr.
// ---------------------------------------------------------------------------
__global__ __launch_bounds__(256) void transpose_wy_tiled(
    const float* __restrict__ W, bf16* __restrict__ T)   // W: [HID][VOCAB]
{
  __shared__ float tile[64][65];
  const int tx = threadIdx.x & 63, ty = threadIdx.x >> 6;
  const int n0 = blockIdx.x * 64, k0 = blockIdx.y * 64;
  #pragma unroll
  for (int r = ty; r < 64; r += 4)
    tile[r][tx] = W[(size_t)(k0 + r) * VOCAB + n0 + tx];
  __syncthreads();
  #pragma unroll
  for (int r = ty; r < 64; r += 4) {
    const int n = n0 + r, k = k0 + tx;
    const int bn = n >> 8, rr = n & 255;
    const int kt = k >> 6;                       // 0..7
    const int sl = ((k & 63) >> 3) ^ (rr & 7);
    const size_t dst = (((size_t)(bn * 8 + kt) * 2048 + rr * 8 + sl) << 3)
                     + (k & 7);
    T[dst] = (bf16)tile[tx][r];
  }
}

// ---------------------------------------------------------------------------
// Embedding gather (bf16 out, rows >= MROWS zeroed)
// ---------------------------------------------------------------------------
__global__ __launch_bounds__(256) void embed_gather(
    const float* __restrict__ embW, const int* __restrict__ captions,
    bf16* __restrict__ X)
{
  const int r = blockIdx.x;
  const int tid = threadIdx.x;
  if (r < MROWS) {
    const int b = r / T_, t = r % T_;
    const int idx = captions[b * S_ + t];
    float2 v = ((const float2*)(embW + (size_t)idx * EMB))[tid];
    X[(size_t)r * EMB + 2 * tid]     = (bf16)v.x;
    X[(size_t)r * EMB + 2 * tid + 1] = (bf16)v.y;
  } else {
    X[(size_t)r * EMB + 2 * tid]     = (bf16)0.f;
    X[(size_t)r * EMB + 2 * tid + 1] = (bf16)0.f;
  }
}

// ---------------------------------------------------------------------------
// img -> bf16, padded to 128 rows
// ---------------------------------------------------------------------------
__global__ __launch_bounds__(256) void img_to_bf16(
    const float* __restrict__ img, bf16* __restrict__ imgB)
{
  const int r = blockIdx.x;
  const int tid = threadIdx.x;
  #pragma unroll
  for (int j = 0; j < 8; j++) {
    const int c = tid + j * 256;
    const float v = (r < B_) ? img[(size_t)r * IMGF + c] : 0.f;
    imgB[(size_t)r * IMGF + c] = (bf16)v;
  }
}

// ---------------------------------------------------------------------------
// bf16 MFMA GEMM, 128x128 tile, 2-phase (small pre/pimg GEMMs)
// ---------------------------------------------------------------------------
__global__ __launch_bounds__(256) void gemm_bt(
    const bf16* __restrict__ A, const bf16* __restrict__ BT,
    const float* __restrict__ bias, float* __restrict__ C,
    int Mvalid, int N, int K)
{
  __shared__ __align__(16) bf16 As[2][128 * 32];
  __shared__ __align__(16) bf16 Bs[2][128 * 32];
  const int tid  = threadIdx.x;
  const int wave = tid >> 6, lane = tid & 63;
  const int wm = wave >> 1, wn = wave & 1;
  const int bm = blockIdx.x, bn = blockIdx.y;
  const int lg = lane >> 4, lr = lane & 15;

  f32x4 acc[4][4];
  #pragma unroll
  for (int m = 0; m < 4; m++)
    #pragma unroll
    for (int n = 0; n < 4; n++) acc[m][n] = (f32x4){0.f, 0.f, 0.f, 0.f};

  const bf16* Abase = A  + (size_t)bm * 128 * K;
  const bf16* Bbase = BT + (size_t)bn * 128 * K;

  const int c0 = wave * 64 + lane;
  const int r0 = c0 >> 2,  sl0 = (c0 & 3) ^ ((r0 >> 1) & 3);
  const int c1 = 256 + c0;
  const int r1 = c1 >> 2,  sl1 = (c1 & 3) ^ ((r1 >> 1) & 3);

  const int NT = K >> 5;

#define STAGE_TILE(buf, kt)                                                   \
  do {                                                                        \
    gload_lds16(Abase + (size_t)r0 * K + (kt) + sl0 * 8,                      \
                &As[buf][(wave * 64) * 8]);                                   \
    gload_lds16(Abase + (size_t)r1 * K + (kt) + sl1 * 8,                      \
                &As[buf][(256 + wave * 64) * 8]);                             \
    gload_lds16(Bbase + (size_t)r0 * K + (kt) + sl0 * 8,                      \
                &Bs[buf][(wave * 64) * 8]);                                   \
    gload_lds16(Bbase + (size_t)r1 * K + (kt) + sl1 * 8,                      \
                &Bs[buf][(256 + wave * 64) * 8]);                             \
  } while (0)

  STAGE_TILE(0, 0);
  int cur = 0;
  for (int it = 0; it < NT; ++it) {
    __syncthreads();
    if (it + 1 < NT) STAGE_TILE(cur ^ 1, (it + 1) * 32);

    bf16x8 af[4], bfr[4];
    #pragma unroll
    for (int m = 0; m < 4; m++) {
      const int r = wm * 64 + m * 16 + lr;
      const int sp = lg ^ ((r >> 1) & 3);
      af[m] = *(const bf16x8*)&As[cur][r * 32 + sp * 8];
    }
    #pragma unroll
    for (int n = 0; n < 4; n++) {
      const int r = wn * 64 + n * 16 + lr;
      const int sp = lg ^ ((r >> 1) & 3);
      bfr[n] = *(const bf16x8*)&Bs[cur][r * 32 + sp * 8];
    }
    #pragma unroll
    for (int m = 0; m < 4; m++)
      #pragma unroll
      for (int n = 0; n < 4; n++)
        acc[m][n] = __builtin_amdgcn_mfma_f32_16x16x32_bf16(af[m], bfr[n], acc[m][n], 0, 0, 0);
    cur ^= 1;
  }
#undef STAGE_TILE

  const int row0 = bm * 128 + wm * 64 + (lane >> 4) * 4;
  const int col0 = bn * 128 + wn * 64 + lr;
  #pragma unroll
  for (int m = 0; m < 4; m++) {
    #pragma unroll
    for (int n = 0; n < 4; n++) {
      const int col = col0 + n * 16;
      const float bv = bias[col];
      #pragma unroll
      for (int q = 0; q < 4; q++) {
        const int row = row0 + m * 16 + q;
        if (row < Mvalid) C[(size_t)row * N + col] = acc[m][n][q] + bv;
      }
    }
  }
}

// ---------------------------------------------------------------------------
// bf16 MFMA GEMM, 256x256 tile, BK=64, 2-buffer stage-early counted-vmcnt
// (validated R14) + LDS-staged epilogue (validated R12).
// ---------------------------------------------------------------------------
__global__ __launch_bounds__(512, 1) void gemm_bt256(
    const bf16* __restrict__ A, const bf16* __restrict__ Btile,
    const float* __restrict__ bias, float* __restrict__ C,
    int Mvalid, int N, int K)
{
  __shared__ __align__(16) bf16 sm[2][2][256 * 64];   // [buf][A/B][(r*8+slot)*8]
  const int tid  = threadIdx.x;
  const int wave = tid >> 6, lane = tid & 63;
  const int wm = wave >> 2, wn = wave & 3;
  const int lg = lane >> 4, lr = lane & 15;

  // XCD-chunk swizzle (1-D grid, multiple of 8)
  const int id  = blockIdx.x;
  const int cpx = gridDim.x >> 3;
  const int swz = (id & 7) * cpx + (id >> 3);
  const int bm  = swz & 15, bn = swz >> 4;

  f32x4 acc[8][4];
  #pragma unroll
  for (int m = 0; m < 8; m++)
    #pragma unroll
    for (int n = 0; n < 4; n++) acc[m][n] = (f32x4){0.f, 0.f, 0.f, 0.f};

  const bf16* Abase = A + (size_t)bm * 256 * K;

  // staging chunk mapping: 2048 chunks/operand (256 rows x 8 slots), 4/thread
  int rs[4], ss[4];
  #pragma unroll
  for (int i = 0; i < 4; i++) {
    const int c = tid + i * 512;
    rs[i] = c >> 3;
    ss[i] = (c & 7) ^ (rs[i] & 7);
  }

#define STAGE64(buf, kti)                                                     \
  do {                                                                        \
    const bf16* Bt_ = Btile + (((size_t)(bn * 8 + (kti))) << 14);             \
    _Pragma("unroll")                                                         \
    for (int i = 0; i < 4; i++)                                               \
      gload_lds16(Abase + (size_t)rs[i] * K + (kti) * 64 + ss[i] * 8,         \
                  &sm[buf][0][(i * 512 + wave * 64) * 8]);                    \
    _Pragma("unroll")                                                         \
    for (int i = 0; i < 4; i++)                                               \
      gload_lds16(Bt_ + (size_t)(tid + i * 512) * 8,                          \
                  &sm[buf][1][(i * 512 + wave * 64) * 8]);                    \
  } while (0)

  STAGE64(0, 0);
  STAGE64(1, 1);

  #pragma unroll 1
  for (int it = 0; it < 8; ++it) {
    if (it < 7) asm volatile("s_waitcnt vmcnt(8)\n\ts_barrier" ::: "memory");
    else        asm volatile("s_waitcnt vmcnt(0)\n\ts_barrier" ::: "memory");

    const bf16* As_ = sm[it & 1][0];
    const bf16* Bs_ = sm[it & 1][1];
    #pragma unroll
    for (int kk = 0; kk < 2; kk++) {
      bf16x8 af[8], bfr[4];
      #pragma unroll
      for (int m = 0; m < 8; m++) {
        const int r = wm * 128 + m * 16 + lr;
        const int sp = (kk * 4 + lg) ^ (r & 7);
        af[m] = *(const bf16x8*)&As_[(r * 8 + sp) * 8];
      }
      #pragma unroll
      for (int n = 0; n < 4; n++) {
        const int r = wn * 64 + n * 16 + lr;
        const int sp = (kk * 4 + lg) ^ (r & 7);
        bfr[n] = *(const bf16x8*)&Bs_[(r * 8 + sp) * 8];
      }
      #pragma unroll
      for (int m = 0; m < 8; m++)
        #pragma unroll
        for (int n = 0; n < 4; n++)
          acc[m][n] = __builtin_amdgcn_mfma_f32_16x16x32_bf16(af[m], bfr[n], acc[m][n], 0, 0, 0);
    }

    LGKM_BARRIER();                   // all waves done READING buf[it]
    if (it + 2 < 8) STAGE64(it & 1, it + 2);
  }
#undef STAGE64

  // ---- LDS-staged epilogue: coalesced dwordx4 C stores (validated R12) ----
  float* cst = (float*)&sm[0][0][0];            // 128 KB = 128 rows x 256 f32
  float bvv[4];
  #pragma unroll
  for (int n = 0; n < 4; n++)
    bvv[n] = bias[bn * 256 + wn * 64 + n * 16 + lr];

  #pragma unroll
  for (int pass = 0; pass < 2; ++pass) {
    if (wm == pass) {
      #pragma unroll
      for (int m = 0; m < 8; m++)
        #pragma unroll
        for (int n = 0; n < 4; n++) {
          const int cc = wn * 64 + n * 16 + lr;
          #pragma unroll
          for (int q = 0; q < 4; q++)
            cst[(m * 16 + lg * 4 + q) * 256 + cc] = acc[m][n][q] + bvv[n];
        }
    }
    __syncthreads();
    const int rbase = bm * 256 + pass * 128;
    #pragma unroll
    for (int i = 0; i < 16; i++) {
      const int r = i * 8 + wave;
      const int grow = rbase + r;
      if (grow < Mvalid) {
        const f32x4 v = *(const f32x4*)&cst[r * 256 + lane * 4];
        *(f32x4*)&C[(size_t)grow * N + bn * 256 + lane * 4] = v;
      }
    }
    __syncthreads();
  }
}

// ---------------------------------------------------------------------------
// Persistent RNN, 8-wave — R14/R12/R9 body, UNCHANGED except the register
// allocation attribute: amdgpu_waves_per_eu(1,2) permits the full 256-arch-
// VGPR budget (bw[48]=192 regs + acc/prq/addressing ≈ 236 needed) instead of
// the 128-reg allocation every 512-thread kernel has been getting (spilling
// ~100 regs to scratch, reloaded all 63 steps).
// ---------------------------------------------------------------------------
#define FREG 48
#define FLDS 16   // 64 - FREG
__global__ __launch_bounds__(512)
__attribute__((amdgpu_waves_per_eu(1, 2)))
void rnn_reg8(
    const float* __restrict__ pre, const bf16* __restrict__ WhT,
    const float* __restrict__ bh, const float* __restrict__ pimg,
    bf16* __restrict__ hs)
{
  const int bg  = blockIdx.x;          // batch group 0..3
  const int tid = threadIdx.x;
  const int wave = tid >> 6, lane = tid & 63;
  const int lg = lane >> 4, lr = lane & 15;
  const int gb0 = bg * 16;             // first batch of block
  const int wc0 = wave * 64;           // first col of wave

  __shared__ __align__(16) bf16 hsh[16 * 512];              // 16 KB
  __shared__ __align__(16) bf16 bls[8 * FLDS * 64 * 8];     // 128 KB

  bf16x8 bw[FREG];
  #pragma unroll
  for (int f = 0; f < 64; f++) {
    const int n = f >> 4, kf = f & 15;
    const bf16x8 v = *(const bf16x8*)(WhT + (size_t)(wc0 + n * 16 + lr) * 512
                                          + kf * 32 + lg * 8);
    if (f < FREG) bw[f] = v;
    else *(bf16x8*)&bls[((wave * FLDS + (f - FREG)) * 64 + lane) * 8] = v;
  }

  *(f32x4*)&hsh[tid * 16]     = (f32x4){0.f, 0.f, 0.f, 0.f};
  *(f32x4*)&hsh[tid * 16 + 8] = (f32x4){0.f, 0.f, 0.f, 0.f};

  float bhv[4];
  #pragma unroll
  for (int n = 0; n < 4; n++) bhv[n] = bh[wc0 + n * 16 + lr];
  const float* preb = pre + ((size_t)(gb0 + lg * 4) * T_) * 512 + wc0 + lr;

  __syncthreads();

  #pragma unroll 1
  for (int t = 0; t < T_; t++) {
    float prq[4][4];
    #pragma unroll
    for (int n = 0; n < 4; n++)
      #pragma unroll
      for (int q = 0; q < 4; q++)
        prq[n][q] = preb[(size_t)q * (T_ * 512) + (size_t)t * 512 + n * 16];

    f32x4 acc[4];
    #pragma unroll
    for (int n = 0; n < 4; n++) acc[n] = (f32x4){0.f, 0.f, 0.f, 0.f};

    #pragma unroll
    for (int kf = 0; kf < 16; kf++) {
      const int c = (kf * 4 + lg) ^ (lr & 7);
      const bf16x8 a = *(const bf16x8*)&hsh[(lr * 64 + c) * 8];
      #pragma unroll
      for (int n = 0; n < 4; n++) {
        const int f = n * 16 + kf;
        bf16x8 bfrag;
        if (f < FREG) bfrag = bw[f];
        else bfrag = *(const bf16x8*)&bls[((wave * FLDS + (f - FREG)) * 64 + lane) * 8];
        acc[n] = __builtin_amdgcn_mfma_f32_16x16x32_bf16(a, bfrag, acc[n], 0, 0, 0);
      }
    }
    LGKM_BARRIER();

    #pragma unroll
    for (int n = 0; n < 4; n++) {
      #pragma unroll
      for (int q = 0; q < 4; q++) {
        const int bl = lg * 4 + q;
        const int b  = gb0 + bl;
        const int k  = wc0 + n * 16 + lr;
        float s = acc[n][q] + prq[n][q] + bhv[n];
        if (t == 0) s += pimg[(size_t)b * HID + k];
        const float e = __builtin_exp2f(s * 2.885390081777927f);
        const float hv = 1.f - 2.f * __builtin_amdgcn_rcpf(e + 1.f);
        hs[((size_t)b * T_ + t) * HID + k] = (bf16)hv;
        const int c = (k >> 3) ^ (bl & 7);
        hsh[bl * 512 + c * 8 + (k & 7)] = (bf16)hv;
      }
    }
    LGKM_BARRIER();
  }
}

// ---------------------------------------------------------------------------
extern "C" void kernel_launch(void* const* d_in, const int* in_sizes, int n_in,
                              void* d_out, int out_size, void* d_ws, size_t ws_size,
                              hipStream_t stream) {
  const float* img      = (const float*)d_in[0];
  const int*   captions = (const int*)d_in[1];
  const float* embW     = (const float*)d_in[2];
  const float* Wi       = (const float*)d_in[3];
  const float* bi       = (const float*)d_in[4];
  const float* Wx       = (const float*)d_in[5];
  const float* bx       = (const float*)d_in[6];
  const float* Wh       = (const float*)d_in[7];
  const float* bh       = (const float*)d_in[8];
  const float* Wy       = (const float*)d_in[9];
  const float* by       = (const float*)d_in[10];
  float* logits = (float*)d_out;

  // workspace layout (52.8 MB; WhT aliases WxT which is dead after pre-GEMM)
  char* ws = (char*)d_ws;
  bf16*  WyT  = (bf16*)(ws);                   // tiled blob, 32,768,000 B
  bf16*  WxT  = (bf16*)(ws + 32768000);        //   512*512*2 =    524,288
  bf16*  X    = (bf16*)(ws + 33292288);        //  4096*512*2 =  4,194,304
  bf16*  hs   = (bf16*)(ws + 37486592);        //  4096*512*2 =  4,194,304
  float* pre  = (float*)(ws + 41680896);       //  4032*512*4 =  8,257,536
  float* pimg = (float*)(ws + 49938432);       //   128*512*4 =    262,144
  bf16*  imgB = (bf16*)(ws + 50200576);        //  128*2048*2 =    524,288
  bf16*  WiT  = (bf16*)(ws + 50724864);        //  512*2048*2 =  2,097,152
  bf16*  WhT  = WxT;                           // alias: used only after pre-GEMM

  // 1) weight transposes / converts to bf16 (Wy -> BK=64 tiled blob)
  transpose_wy_tiled<<<dim3(VOCAB / 64, HID / 64), 256, 0, stream>>>(Wy, WyT);
  transpose_w<<<dim3(HID / 64, EMB / 64), 256, 0, stream>>>(Wx, WxT, EMB, HID);
  transpose_w<<<dim3(HID / 64, IMGF / 64), 256, 0, stream>>>(Wi, WiT, IMGF, HID);
  img_to_bf16<<<128, 256, 0, stream>>>(img, imgB);

  // 2) embedding gather
  embed_gather<<<MPAD, 256, 0, stream>>>(embW, captions, X);

  // 3) pre = X @ Wx + bx
  gemm_bt<<<dim3(MPAD / 128, HID / 128), 256, 0, stream>>>(X, WxT, bx, pre, MROWS, HID, HID);

  // 4) pimg = img @ Wi + bi
  gemm_bt<<<dim3(1, HID / 128), 256, 0, stream>>>(imgB, WiT, bi, pimg, B_, HID, IMGF);

  // 5) Wh -> bf16 [col][k]
  transpose_w<<<dim3(HID / 64, HID / 64), 256, 0, stream>>>(Wh, WhT, HID, HID);

  // 6) zero hs pad rows
  hipMemsetAsync(hs + (size_t)MROWS * HID, 0,
                 (size_t)(MPAD - MROWS) * HID * sizeof(bf16), stream);

  // 7) RNN: all 63 steps, 4 fully-independent blocks (16 batches each)
  rnn_reg8<<<4, 512, 0, stream>>>(pre, WhT, bh, pimg, hs);

  // 8) logits = hs @ Wy + by   [256^2, BK=64, 2-buf counted-vmcnt]
  gemm_bt256<<<(MPAD / 256) * (VOCAB / 256), 512, 0, stream>>>(
      hs, WyT, by, logits, MROWS, VOCAB, HID);
}